// Round 4
// baseline (116.528 us; speedup 1.0000x reference)
//
#include <hip/hip_runtime.h>

#define NPTS 8192
#define BATCH 4
#define BLOCK 256
#define NQ 4                   // queries per thread
#define QPB (BLOCK * NQ)       // 1024 queries per block
#define QBLOCKS (NPTS / QPB)   // 8
#define GROUPS 16              // target groups (partial-min slots per query)
#define GRP_SHIFT 4
#define TPB (NPTS / GROUPS)    // 512 targets per block
#define LDSPTS TPB

// ---------------------------------------------------------------------------
// chamfer: grid (QBLOCKS*GROUPS, BATCH, 2) = 1024 blocks (4 waves/SIMD).
// R4: scalar-FMA rewrite. R0-R3 established: busy time pinned at ~27 us,
// idle ~40% immune to SW pipelining, launch bounds, and block restructure.
// Arithmetic: executed pk_fma work = 24 us at 4cy throughput (matches
// VALUBusy), but duration matches chains serialized at dependent latency
// (~8-14 cy/fma): per-wave duty 29% x 2 waves/SIMD = 58% = measured.
// Root cause: packed v2f splats burn 48 VGPRs on duplicated values, so at
// the 64-VGPR allocation regalloc cannot keep 16 independent chains live
// and the scheduler serializes them. Scalar form: 3 regs/query splat,
// 1 reg/chain -> 8 independent scalar chains interleave within 64 VGPRs,
// plus 4 waves/SIMD of TLP as backstop. Same FLOP count and pipe time.
// LDS: tgt[t] = {x, y, z, |q|^2}; all lanes read the same address per
// iteration (b128 broadcast, conflict-free, proven cheap R0-R3).
// Plain partial-min stores per (query, group); no atomics, no memset.
// Block (0,0,0) zeroes out[0]. Workspace: 2*B*GROUPS*NPTS floats = 4 MiB.
// ---------------------------------------------------------------------------
__global__ __launch_bounds__(256) void chamfer_kernel(
    const float* __restrict__ x, const float* __restrict__ y,
    float* __restrict__ mins, float* __restrict__ out) {
    __shared__ float4 tgt[LDSPTS];

    if (blockIdx.x == 0 && blockIdx.y == 0 && blockIdx.z == 0 && threadIdx.x == 0)
        out[0] = 0.0f;

    const int dir = blockIdx.z;
    const int b = blockIdx.y;
    const int g = blockIdx.x & (GROUPS - 1);
    const int qb = blockIdx.x >> GRP_SHIFT;

    const float* pts = dir ? y : x;  // query set
    const float* oth = dir ? x : y;  // target set

    // stage 512 targets: each thread owns two consecutive points (24 B read)
    {
        const int t = threadIdx.x;
        const float* q = oth + ((size_t)b * NPTS + g * TPB + 2 * t) * 3;
        const float qx0 = q[0], qy0 = q[1], qz0 = q[2];
        const float qx1 = q[3], qy1 = q[4], qz1 = q[5];
        const float sq0 = fmaf(qz0, qz0, fmaf(qy0, qy0, qx0 * qx0));
        const float sq1 = fmaf(qz1, qz1, fmaf(qy1, qy1, qx1 * qx1));
        tgt[2 * t]     = (float4){qx0, qy0, qz0, sq0};
        tgt[2 * t + 1] = (float4){qx1, qy1, qz1, sq1};
    }

    // query splats: -2*p per component (scalar, 3 regs/query), |p|^2 folded
    // in at the end.
    float nx[NQ], ny[NQ], nz[NQ], sp[NQ], best[NQ];
    const int qbase = b * NPTS + qb * QPB + (int)threadIdx.x;
#pragma unroll
    for (int k = 0; k < NQ; ++k) {
        const float* p = pts + (size_t)(qbase + k * BLOCK) * 3;
        const float px = p[0], py = p[1], pz = p[2];
        nx[k] = -2.0f * px;
        ny[k] = -2.0f * py;
        nz[k] = -2.0f * pz;
        sp[k] = fmaf(pz, pz, fmaf(py, py, px * px));
        best[k] = 3.0e38f;
    }

    __syncthreads();

#pragma unroll 2
    for (int j = 0; j < TPB; j += 2) {
        const float4 t0 = tgt[j];
        const float4 t1 = tgt[j + 1];
#pragma unroll
        for (int k = 0; k < NQ; ++k) {
            // two independent 3-deep scalar FMA chains per query
            float d0 = fmaf(nx[k], t0.x, t0.w);
            float d1 = fmaf(nx[k], t1.x, t1.w);
            d0 = fmaf(ny[k], t0.y, d0);
            d1 = fmaf(ny[k], t1.y, d1);
            d0 = fmaf(nz[k], t0.z, d0);
            d1 = fmaf(nz[k], t1.z, d1);
            best[k] = fminf(best[k], fminf(d0, d1));  // v_min3_f32
        }
    }

    // plain coalesced stores of this group's partial min per query
    float* om = mins + ((size_t)((dir * BATCH + b) * GROUPS + g)) * NPTS +
                qb * QPB + threadIdx.x;
#pragma unroll
    for (int k = 0; k < NQ; ++k)
        om[k * BLOCK] = fmaxf(sp[k] + best[k], 0.0f);
}

// ---------------------------------------------------------------------------
// finalize: 64 blocks x 256 threads. Each thread owns 4 adjacent queries of
// one (dir,b) slice: min-reduces the 16 group partials (float4 loads,
// coalesced within each group slice), sums the 4 mins * 1/(B*N) -- the
// exact same sum tree as before. gid 0 adds the regularizer. Block reduce
// + atomicAdd into out[0].
// ---------------------------------------------------------------------------
__global__ __launch_bounds__(256) void finalize_kernel(
    const float* __restrict__ mins, const float* __restrict__ R,
    const float* __restrict__ S, const float* __restrict__ t,
    const float* __restrict__ R_gt, const float* __restrict__ S_gt,
    const float* __restrict__ t_gt, float* __restrict__ out) {
    const float4* m4 = (const float4*)mins;  // [8][GROUPS][NPTS/4]
    const int gid = blockIdx.x * 256 + (int)threadIdx.x;  // 0..16383
    const int db = gid >> 11;       // dir*BATCH+b, 0..7
    const int qi = gid & 2047;      // float4 index within slice

    float4 mn = m4[(size_t)(db * GROUPS) * (NPTS / 4) + qi];
#pragma unroll
    for (int gg = 1; gg < GROUPS; ++gg) {
        const float4 u = m4[(size_t)(db * GROUPS + gg) * (NPTS / 4) + qi];
        mn.x = fminf(mn.x, u.x);
        mn.y = fminf(mn.y, u.y);
        mn.z = fminf(mn.z, u.z);
        mn.w = fminf(mn.w, u.w);
    }
    float v = (mn.x + mn.y + mn.z + mn.w) * (1.0f / (BATCH * NPTS));

    if (gid == 0) {
        float acc = 0.0f;
        for (int b = 0; b < BATCH; ++b)
            for (int i = 0; i < 3; ++i)
                for (int k = 0; k < 3; ++k) {
                    float s = 0.0f;
                    for (int j = 0; j < 3; ++j)
                        s += R_gt[b * 9 + j * 3 + i] * R[b * 9 + j * 3 + k];
                    s -= (i == k) ? 1.0f : 0.0f;
                    acc += s * s;
                }
        for (int d = 0; d < 3; ++d)  // jnp.diagonal(S, axis1=0, axis2=1)
            for (int a = 0; a < 3; ++a) {
                const float diff = S[d * 9 + d * 3 + a] - S_gt[d * 9 + d * 3 + a];
                acc += diff * diff;
            }
        for (int b = 0; b < BATCH; ++b)
            for (int k = 0; k < 3; ++k) {
                const float diff = t[b * 3 + k] - t_gt[b * 3 + k];
                acc += diff * diff;
            }
        v += acc;
    }

    // block reduction: 4 waves of 64
    for (int off = 32; off; off >>= 1) v += __shfl_down(v, off, 64);
    __shared__ float wsum[4];
    const int lane = threadIdx.x & 63;
    const int wave = threadIdx.x >> 6;
    if (lane == 0) wsum[wave] = v;
    __syncthreads();
    if (wave == 0) {
        v = (lane < 4) ? wsum[lane] : 0.0f;
        for (int off = 2; off; off >>= 1) v += __shfl_down(v, off, 64);
        if (lane == 0) atomicAdd(out, v);
    }
}

extern "C" void kernel_launch(void* const* d_in, const int* in_sizes, int n_in,
                              void* d_out, int out_size, void* d_ws, size_t ws_size,
                              hipStream_t stream) {
    const float* x    = (const float*)d_in[0];
    const float* y    = (const float*)d_in[1];
    const float* R    = (const float*)d_in[2];
    const float* S    = (const float*)d_in[3];
    const float* t    = (const float*)d_in[4];
    const float* R_gt = (const float*)d_in[5];
    const float* S_gt = (const float*)d_in[6];
    const float* t_gt = (const float*)d_in[7];
    float* out = (float*)d_out;
    float* mins = (float*)d_ws;  // 2*BATCH*GROUPS*NPTS floats = 4 MiB

    chamfer_kernel<<<dim3(QBLOCKS * GROUPS, BATCH, 2), dim3(BLOCK), 0, stream>>>(
        x, y, mins, out);

    finalize_kernel<<<dim3(2 * BATCH * NPTS / 4 / 256), dim3(BLOCK), 0, stream>>>(
        mins, R, S, t, R_gt, S_gt, t_gt, out);
}